// Round 1
// baseline (1319.944 us; speedup 1.0000x reference)
//
#include <hip/hip_runtime.h>
#include <math.h>

#define E_TOT   10240
#define N_NODES 512
#define NCOL    11520
#define ME      20          // edges per workgroup in k3 (512 WGs * 20 = 10240)

constexpr float EPSF        = 1e-5f;
constexpr float INV_SQRT128 = 0.08838834764831845f;
constexpr float INV_SQRT112 = 0.09449111825230681f;
constexpr float INV_SQRT48  = 0.14433756729740643f;
constexpr float INV_SQRT32  = 0.17677669529663687f;
constexpr float INV_SQRT16  = 0.25f;
constexpr float INV_SQRT8   = 0.35355339059327373f;
constexpr float SC0 = INV_SQRT128 * INV_SQRT112;   // out0 scale
constexpr float SC1 = INV_SQRT128 * INV_SQRT48;    // op1/on1 scale
constexpr float SC2 = INV_SQRT128 * INV_SQRT16;    // op2/on2 scale
constexpr float C_OLD_ = 0.8944271909999159f;
constexpr float C_NEW_ = 0.4472135954999579f;
constexpr float NORMC  = 0.22360679774997896f;

// ---------------------------------------------------------------- utilities
__device__ __forceinline__ float wsum(float v) {
#pragma unroll
  for (int off = 32; off > 0; off >>= 1) v += __shfl_xor(v, off, 64);
  return v;
}

// Analytic Wigner-D (l=2) in basis {xy, yz, 3z^2-1, xz, x^2-y^2} for rotation
// with rows q0,q1,q2 (packed q[9]).  D[b][c]: y2_b(Q p) = sum_c D[b][c] y2_c(p).
__device__ __forceinline__ void wigner5(const float q[9], float D[25]) {
  const float q0x=q[0],q0y=q[1],q0z=q[2];
  const float q1x=q[3],q1y=q[4],q1z=q[5];
  const float q2x=q[6],q2y=q[7],q2z=q[8];
  // row0: sym(q0,q1)   (x'y')
  D[0]  = q0x*q1y + q1x*q0y;
  D[1]  = q0y*q1z + q1y*q0z;
  D[2]  = 0.5f*(q0z*q1z);
  D[3]  = q0x*q1z + q1x*q0z;
  D[4]  = 0.5f*(q0x*q1x - q0y*q1y);
  // row1: sym(q1,q2)   (y'z')
  D[5]  = q1x*q2y + q2x*q1y;
  D[6]  = q1y*q2z + q2y*q1z;
  D[7]  = 0.5f*(q1z*q2z);
  D[8]  = q1x*q2z + q2x*q1z;
  D[9]  = 0.5f*(q1x*q2x - q1y*q2y);
  // row2: 3 q2 (x) q2 - I   (3z'^2-1)
  D[10] = 6.f*q2x*q2y;
  D[11] = 6.f*q2y*q2z;
  D[12] = 0.5f*(3.f*q2z*q2z - 1.f);
  D[13] = 6.f*q2x*q2z;
  D[14] = 1.5f*(q2x*q2x - q2y*q2y);
  // row3: sym(q0,q2)   (x'z')
  D[15] = q0x*q2y + q2x*q0y;
  D[16] = q0y*q2z + q2y*q0z;
  D[17] = 0.5f*(q0z*q2z);
  D[18] = q0x*q2z + q2x*q0z;
  D[19] = 0.5f*(q0x*q2x - q0y*q2y);
  // row4: q0(x)q0 - q1(x)q1   (x'^2-y'^2)
  D[20] = 2.f*(q0x*q0y - q1x*q1y);
  D[21] = 2.f*(q0y*q0z - q1y*q1z);
  D[22] = 0.5f*(q0z*q0z - q1z*q1z);
  D[23] = 2.f*(q0x*q0z - q1x*q1z);
  D[24] = 0.5f*((q0x*q0x - q1x*q1x) - (q0y*q0y - q1y*q1y));
}

// ---------------------------------------------------------------- K1: _sln
__global__ void k1_sln(const float* __restrict__ x_all,
                       const float* __restrict__ w0, const float* __restrict__ b0,
                       const float* __restrict__ w1, const float* __restrict__ w2,
                       float* __restrict__ nf) {
  const int n = blockIdx.x;
  const int t = threadIdx.x;
  const float* x = x_all + n*120;
  float xs = (t < 32) ? x[t] : 0.f;
  float ssum = wsum(xs);
  float ssq  = wsum(xs*xs);
  float mu   = ssum * (1.f/32.f);
  float var  = ssq * (1.f/32.f) - mu*mu;
  float istd = rsqrtf(var + EPSF);
  float q1 = (t < 48) ? x[32+t] : 0.f;
  float v1s = wsum(q1*q1);
  float q2 = (t < 40) ? x[80+t] : 0.f;
  float v2s = wsum(q2*q2);
  float inv = rsqrtf(0.5f*(v1s*(1.f/48.f) + v2s*(1.f/40.f)) + EPSF);
  for (int j = t; j < 120; j += 64) {
    float val = x[j], r;
    if (j < 32)      r = (val - mu)*istd*w0[j] + b0[j];
    else if (j < 80) r = val*inv*w1[(j-32)/3];
    else             r = val*inv*w2[(j-80)/5];
    nf[n*120 + j] = r;
  }
}

// ------------------------------------------------- K2: per-edge preprocessing
__global__ void k2_edge_prep(const float* __restrict__ lat,
                             const float* __restrict__ hid,
                             const float* __restrict__ evec,
                             const float* __restrict__ Wenv,
                             const int*   __restrict__ eidx,
                             const int*   __restrict__ act,
                             const float* __restrict__ nf,
                             float* __restrict__ invec,
                             float* __restrict__ Rm,
                             float* __restrict__ D2bm,
                             float* __restrict__ wenvo) {
  const int e = blockIdx.x*blockDim.x + threadIdx.x;
  if (e >= E_TOT) return;
  const int ae  = act[e];
  const int ctr = eidx[ae];               // edge_index row 0
  // ---- frame
  float vx = evec[ae*3+0], vy = evec[ae*3+1], vz = evec[ae*3+2];
  float rn = rsqrtf(vx*vx + vy*vy + vz*vz);
  float nx = vx*rn, ny = vy*rn, nz = vz*rn;
  float e1x, e1y, e1z;
  if (fabsf(nz) < 0.99f) { e1x = -ny; e1y = nx;  e1z = 0.f; }   // cross(z, n)
  else                   { e1x = 0.f; e1y = -nz; e1z = ny;  }   // cross(x, n)
  float rl = rsqrtf(e1x*e1x + e1y*e1y + e1z*e1z);
  e1x *= rl; e1y *= rl; e1z *= rl;
  float e2x = ny*e1z - nz*e1y;
  float e2y = nz*e1x - nx*e1z;
  float e2z = nx*e1y - ny*e1x;
  float R[9] = {e1x,e1y,e1z, e2x,e2y,e2z, nx,ny,nz};
#pragma unroll
  for (int j = 0; j < 9; ++j) Rm[e*9 + j] = R[j];
  float Df[25];
  wigner5(R, Df);
  float Rt[9] = {R[0],R[3],R[6], R[1],R[4],R[7], R[2],R[5],R[8]};
  float Db[25];
  wigner5(Rt, Db);
#pragma unroll
  for (int j = 0; j < 25; ++j) D2bm[e*25 + j] = Db[j];
  // ---- build so2 input vectors
  const float* xa = nf  + (size_t)ctr*120;
  const float* xb = hid + (size_t)e*120;
  float* iv = invec + (size_t)e*240;
  // in0 layout: [0:64 s | 64:96 v1.y | 96:112 v2.c2]; inn1 @112 (48);
  // inp1 @160 (48); inn2 @208 (16); inp2 @224 (16)
#pragma unroll
  for (int j = 0; j < 32; ++j) { iv[j] = xa[j]; iv[32+j] = xb[j]; }
#pragma unroll
  for (int u = 0; u < 32; ++u) {
    const float* src = (u < 16) ? (xa + 32 + 3*u) : (xb + 32 + 3*(u-16));
    float px = src[0], py = src[1], pz = src[2];
    float rx = R[0]*px + R[1]*py + R[2]*pz;
    float ry = R[3]*px + R[4]*py + R[5]*pz;
    float rz = R[6]*px + R[7]*py + R[8]*pz;
    iv[64+u]  = ry;   // in0
    iv[112+u] = rx;   // inn1
    iv[160+u] = rz;   // inp1
  }
#pragma unroll
  for (int u = 0; u < 16; ++u) {
    const float* src = (u < 8) ? (xa + 80 + 5*u) : (xb + 80 + 5*(u-8));
    float p0 = src[0], p1 = src[1], p2 = src[2], p3 = src[3], p4 = src[4];
    float d[5];
#pragma unroll
    for (int i = 0; i < 5; ++i)
      d[i] = Df[i*5+0]*p0 + Df[i*5+1]*p1 + Df[i*5+2]*p2 + Df[i*5+3]*p3 + Df[i*5+4]*p4;
    iv[96+u]  = d[2];   // in0
    iv[144+u] = d[1];   // inn1 tail
    iv[192+u] = d[3];   // inp1 tail
    iv[208+u] = d[0];   // inn2
    iv[224+u] = d[4];   // inp2
  }
  // ---- wenv = latents[ae] @ W_env / sqrt(128)
  float we[56];
#pragma unroll
  for (int o = 0; o < 56; ++o) we[o] = 0.f;
  const float* lrow = lat + (size_t)ae*128;
  for (int l = 0; l < 128; ++l) {
    float lv = lrow[l];
    const float* wr = Wenv + l*56;
#pragma unroll
    for (int o = 0; o < 56; ++o) we[o] += lv * wr[o];
  }
#pragma unroll
  for (int o = 0; o < 56; ++o) wenvo[(size_t)e*56 + o] = we[o] * INV_SQRT128;
}

// --------------------------- K3: fused wdyn GEMM + so2 contraction + epilogue
__device__ __forceinline__ void contract_col(int c, const float* a,
                                             const float* invs, float* oa) {
  if (c < 8960) {
    int i = c/80, o = c - i*80;
#pragma unroll
    for (int e = 0; e < ME; ++e)
      atomicAdd(&oa[e*144 + o], a[e]*invs[e*240 + i]);
  } else if (c < 10112) {              // w1r
    int cc = c - 8960; int i = cc/24, o = cc - i*24;
#pragma unroll
    for (int e = 0; e < ME; ++e) {
      float w = a[e];
      atomicAdd(&oa[e*144 + 80  + o],  w*invs[e*240 + 160 + i]);  // op1 += inp1*w
      atomicAdd(&oa[e*144 + 104 + o],  w*invs[e*240 + 112 + i]);  // on1 += inn1*w
    }
  } else if (c < 11264) {              // w1i
    int cc = c - 10112; int i = cc/24, o = cc - i*24;
#pragma unroll
    for (int e = 0; e < ME; ++e) {
      float w = a[e];
      atomicAdd(&oa[e*144 + 80  + o], -w*invs[e*240 + 112 + i]);  // op1 -= inn1*w
      atomicAdd(&oa[e*144 + 104 + o],  w*invs[e*240 + 160 + i]);  // on1 += inp1*w
    }
  } else if (c < 11392) {              // w2r
    int cc = c - 11264; int i = cc/8, o = cc - i*8;
#pragma unroll
    for (int e = 0; e < ME; ++e) {
      float w = a[e];
      atomicAdd(&oa[e*144 + 128 + o],  w*invs[e*240 + 224 + i]);  // op2 += inp2*w
      atomicAdd(&oa[e*144 + 136 + o],  w*invs[e*240 + 208 + i]);  // on2 += inn2*w
    }
  } else {                             // w2i
    int cc = c - 11392; int i = cc/8, o = cc - i*8;
#pragma unroll
    for (int e = 0; e < ME; ++e) {
      float w = a[e];
      atomicAdd(&oa[e*144 + 128 + o], -w*invs[e*240 + 208 + i]);  // op2 -= inn2*w
      atomicAdd(&oa[e*144 + 136 + o],  w*invs[e*240 + 224 + i]);  // on2 += inp2*w
    }
  }
}

__global__ __launch_bounds__(256, 2)
void k3_main(const float* __restrict__ lat,
             const float* __restrict__ Wtp,
             const float* __restrict__ invg,
             const float* __restrict__ Rm,
             const float* __restrict__ D2bm,
             const float* __restrict__ wenvg,
             const int*   __restrict__ eidx,
             const int*   __restrict__ act,
             const float* __restrict__ Wp0,
             const float* __restrict__ bp0,
             const float* __restrict__ Wp1,
             const float* __restrict__ Wp2,
             float* __restrict__ accg) {
  __shared__ float4 lat4[ME*32];            // [e][l/4]
  __shared__ float  invs[ME*240];
  __shared__ float  oa[ME*144];             // [out0 80|op1 24|on1 24|op2 8|on2 8]
  const int t = threadIdx.x;
  const int ebase = blockIdx.x * ME;
  float* lats = (float*)lat4;
  for (int i = t; i < ME*128; i += 256) lats[i] = lat[(size_t)ebase*128 + i];
  for (int i = t; i < ME*240; i += 256) invs[i] = invg[(size_t)ebase*240 + i];
  for (int i = t; i < ME*144; i += 256) oa[i]   = 0.f;
  __syncthreads();

  for (int m = 0; m < 15; ++m) {
    const int c0 = t + 768*m;              // columns c0, c0+256, c0+512
    float a0[ME], a1[ME], a2[ME];
#pragma unroll
    for (int e = 0; e < ME; ++e) { a0[e] = 0.f; a1[e] = 0.f; a2[e] = 0.f; }
    for (int l0 = 0; l0 < 32; ++l0) {
      const float* wb = Wtp + (size_t)(l0*4)*NCOL + c0;
      float wA0 = wb[0],          wA1 = wb[NCOL],       wA2 = wb[2*NCOL],       wA3 = wb[3*NCOL];
      float wB0 = wb[256],        wB1 = wb[NCOL+256],   wB2 = wb[2*NCOL+256],   wB3 = wb[3*NCOL+256];
      float wC0 = wb[512],        wC1 = wb[NCOL+512],   wC2 = wb[2*NCOL+512],   wC3 = wb[3*NCOL+512];
#pragma unroll
      for (int e = 0; e < ME; ++e) {
        float4 lv = lat4[e*32 + l0];
        a0[e] += lv.x*wA0; a0[e] += lv.y*wA1; a0[e] += lv.z*wA2; a0[e] += lv.w*wA3;
        a1[e] += lv.x*wB0; a1[e] += lv.y*wB1; a1[e] += lv.z*wB2; a1[e] += lv.w*wB3;
        a2[e] += lv.x*wC0; a2[e] += lv.y*wC1; a2[e] += lv.z*wC2; a2[e] += lv.w*wC3;
      }
    }
    contract_col(c0,       a0, invs, oa);
    contract_col(c0 + 256, a1, invs, oa);
    contract_col(c0 + 512, a2, invs, oa);
  }
  __syncthreads();

  // ---- epilogue: one thread per edge
  if (t < ME) {
    const int eg = ebase + t;
    const float* o_ = oa + t*144;
    const float* Rr = Rm   + (size_t)eg*9;
    const float* Db = D2bm + (size_t)eg*25;
    const float* we = wenvg + (size_t)eg*56;
    const int ae2 = act[eg];
    const int ctr = eidx[ae2];
    float* dst = accg + (size_t)ctr*120;

    float sg[32], g[24];
#pragma unroll
    for (int j = 0; j < 32; ++j) { float s = o_[j]*SC0; sg[j] = s/(1.f + expf(-s)); }
#pragma unroll
    for (int j = 0; j < 24; ++j) { float s = o_[32+j]*SC0; g[j] = 1.f/(1.f + expf(-s)); }

    // scalar channel: ir_linear + env + scatter
#pragma unroll
    for (int o2 = 0; o2 < 32; ++o2) {
      float s = 0.f;
#pragma unroll
      for (int i = 0; i < 32; ++i) s += sg[i]*Wp0[i*32 + o2];
      s = s*INV_SQRT32 + bp0[o2];
      atomicAdd(&dst[o2], s*we[o2]);
    }
    // v1 channel
    float acc1[48];
#pragma unroll
    for (int i = 0; i < 48; ++i) acc1[i] = 0.f;
#pragma unroll
    for (int u = 0; u < 16; ++u) {
      float yx = o_[104+u]*SC1;   // on1[u]
      float yy = o_[56+u]*SC0;    // out0[56+u]
      float yz = o_[80+u]*SC1;    // op1[u]
      float px = Rr[0]*yx + Rr[3]*yy + Rr[6]*yz;   // R^T rotate back
      float py = Rr[1]*yx + Rr[4]*yy + Rr[7]*yz;
      float pz = Rr[2]*yx + Rr[5]*yy + Rr[8]*yz;
      float gu = g[u];
      px *= gu; py *= gu; pz *= gu;
#pragma unroll
      for (int v = 0; v < 16; ++v) {
        float wp = Wp1[u*16 + v];
        acc1[v*3+0] += px*wp; acc1[v*3+1] += py*wp; acc1[v*3+2] += pz*wp;
      }
    }
#pragma unroll
    for (int v = 0; v < 16; ++v) {
      float sc = INV_SQRT16*we[32+v];
      atomicAdd(&dst[32+v*3+0], acc1[v*3+0]*sc);
      atomicAdd(&dst[32+v*3+1], acc1[v*3+1]*sc);
      atomicAdd(&dst[32+v*3+2], acc1[v*3+2]*sc);
    }
    // v2 channel
    float acc2[40];
#pragma unroll
    for (int i = 0; i < 40; ++i) acc2[i] = 0.f;
#pragma unroll
    for (int u = 0; u < 8; ++u) {
      float y0 = o_[136+u]*SC2;   // on2[u]
      float y1 = o_[120+u]*SC1;   // on1[16+u]
      float y2 = o_[72+u]*SC0;    // out0[72+u]
      float y3 = o_[96+u]*SC1;    // op1[16+u]
      float y4 = o_[128+u]*SC2;   // op2[u]
      float p[5];
#pragma unroll
      for (int i = 0; i < 5; ++i)
        p[i] = Db[i*5+0]*y0 + Db[i*5+1]*y1 + Db[i*5+2]*y2 + Db[i*5+3]*y3 + Db[i*5+4]*y4;
      float gu = g[16+u];
#pragma unroll
      for (int i = 0; i < 5; ++i) p[i] *= gu;
#pragma unroll
      for (int v = 0; v < 8; ++v) {
        float wp = Wp2[u*8 + v];
#pragma unroll
        for (int i = 0; i < 5; ++i) acc2[v*5+i] += p[i]*wp;
      }
    }
#pragma unroll
    for (int v = 0; v < 8; ++v) {
      float sc = INV_SQRT8*we[48+v];
#pragma unroll
      for (int i = 0; i < 5; ++i) atomicAdd(&dst[80+v*5+i], acc2[v*5+i]*sc);
    }
  }
}

// -------------------------------------------- K5: residual path + combine
__global__ void k5_final(const float* __restrict__ x_all,
                         const float* __restrict__ Wr0, const float* __restrict__ br0,
                         const float* __restrict__ Wr1, const float* __restrict__ Wr2,
                         const float* __restrict__ accg,
                         float* __restrict__ out) {
  const int n = blockIdx.x;
  const int t = threadIdx.x;
  if (t >= 120) return;
  const float* x = x_all + n*120;
  float r;
  if (t < 32) {
    float s = 0.f;
#pragma unroll
    for (int i = 0; i < 32; ++i) s += x[i]*Wr0[i*32 + t];
    r = s*INV_SQRT32 + br0[t];
  } else if (t < 80) {
    int j = t - 32, v = j/3, cp = j - 3*v;
    float s = 0.f;
#pragma unroll
    for (int u = 0; u < 16; ++u) s += x[32 + u*3 + cp]*Wr1[u*16 + v];
    r = s*INV_SQRT16;
  } else {
    int j = t - 80, v = j/5, cp = j - 5*v;
    float s = 0.f;
#pragma unroll
    for (int u = 0; u < 8; ++u) s += x[80 + u*5 + cp]*Wr2[u*8 + v];
    r = s*INV_SQRT8;
  }
  out[n*120 + t] = C_NEW_*(NORMC*accg[n*120 + t]) + C_OLD_*r;
}

// ---------------------------------------------------------------- launcher
extern "C" void kernel_launch(void* const* d_in, const int* in_sizes, int n_in,
                              void* d_out, int out_size, void* d_ws, size_t ws_size,
                              hipStream_t stream) {
  const float* lat  = (const float*)d_in[0];
  const float* ndf  = (const float*)d_in[1];
  const float* hid  = (const float*)d_in[2];
  const float* evec = (const float*)d_in[4];
  const float* Wtp  = (const float*)d_in[5];
  const float* Wenv = (const float*)d_in[6];
  const float* w0   = (const float*)d_in[7];
  const float* b0   = (const float*)d_in[8];
  const float* w1   = (const float*)d_in[9];
  const float* w2   = (const float*)d_in[10];
  const float* Wp0  = (const float*)d_in[11];
  const float* bp0  = (const float*)d_in[12];
  const float* Wp1  = (const float*)d_in[13];
  const float* Wp2  = (const float*)d_in[14];
  const float* Wr0  = (const float*)d_in[15];
  const float* br0  = (const float*)d_in[16];
  const float* Wr1  = (const float*)d_in[17];
  const float* Wr2  = (const float*)d_in[18];
  const int*   eidx = (const int*)d_in[20];
  const int*   act  = (const int*)d_in[21];
  float* out = (float*)d_out;

  float* ws    = (float*)d_ws;
  float* nf    = ws;                            // 512*120      = 61440
  float* invec = nf    + 61440;                 // 10240*240    = 2457600
  float* Rm    = invec + 2457600;               // 10240*9      = 92160
  float* D2bm  = Rm    + 92160;                 // 10240*25     = 256000
  float* wenv  = D2bm  + 256000;                // 10240*56     = 573440
  float* accg  = wenv  + 573440;                // 512*120      = 61440

  hipMemsetAsync(accg, 0, (size_t)61440*sizeof(float), stream);
  k1_sln<<<N_NODES, 64, 0, stream>>>(ndf, w0, b0, w1, w2, nf);
  k2_edge_prep<<<E_TOT/256, 256, 0, stream>>>(lat, hid, evec, Wenv, eidx, act,
                                              nf, invec, Rm, D2bm, wenv);
  k3_main<<<E_TOT/ME, 256, 0, stream>>>(lat, Wtp, invec, Rm, D2bm, wenv,
                                        eidx, act, Wp0, bp0, Wp1, Wp2, accg);
  k5_final<<<N_NODES, 128, 0, stream>>>(ndf, Wr0, br0, Wr1, Wr2, accg, out);
}

// Round 2
// 336.393 us; speedup vs baseline: 3.9238x; 3.9238x over previous
//
#include <hip/hip_runtime.h>
#include <math.h>

#define E_TOT   10240
#define N_NODES 512
#define NCOL    11520

typedef unsigned short ushort_t;
typedef unsigned int   uint_t;
typedef __bf16 bf16x8 __attribute__((ext_vector_type(8)));
typedef float  f32x4  __attribute__((ext_vector_type(4)));

constexpr float EPSF        = 1e-5f;
constexpr float INV_SQRT128 = 0.08838834764831845f;
constexpr float INV_SQRT112 = 0.09449111825230681f;
constexpr float INV_SQRT48  = 0.14433756729740643f;
constexpr float INV_SQRT32  = 0.17677669529663687f;
constexpr float INV_SQRT16  = 0.25f;
constexpr float INV_SQRT8   = 0.35355339059327373f;
constexpr float SC0 = INV_SQRT128 * INV_SQRT112;   // out0 scale (folded into Wpack)
constexpr float SC1 = INV_SQRT128 * INV_SQRT48;    // op1/on1 scale
constexpr float SC2 = INV_SQRT128 * INV_SQRT16;    // op2/on2 scale
constexpr float C_OLD_ = 0.8944271909999159f;
constexpr float C_NEW_ = 0.4472135954999579f;
constexpr float NORMC  = 0.22360679774997896f;

// ---------------------------------------------------------------- utilities
__device__ __forceinline__ float wsum(float v) {
#pragma unroll
  for (int off = 32; off > 0; off >>= 1) v += __shfl_xor(v, off, 64);
  return v;
}

__device__ __forceinline__ ushort_t f2bf(float x) {
  uint_t u = __float_as_uint(x);
  u = (u + 0x7fffu + ((u >> 16) & 1u)) >> 16;
  return (ushort_t)u;
}

// Analytic Wigner-D (l=2) in basis {xy, yz, 3z^2-1, xz, x^2-y^2}.
__device__ __forceinline__ void wigner5(const float q[9], float D[25]) {
  const float q0x=q[0],q0y=q[1],q0z=q[2];
  const float q1x=q[3],q1y=q[4],q1z=q[5];
  const float q2x=q[6],q2y=q[7],q2z=q[8];
  D[0]  = q0x*q1y + q1x*q0y;
  D[1]  = q0y*q1z + q1y*q0z;
  D[2]  = 0.5f*(q0z*q1z);
  D[3]  = q0x*q1z + q1x*q0z;
  D[4]  = 0.5f*(q0x*q1x - q0y*q1y);
  D[5]  = q1x*q2y + q2x*q1y;
  D[6]  = q1y*q2z + q2y*q1z;
  D[7]  = 0.5f*(q1z*q2z);
  D[8]  = q1x*q2z + q2x*q1z;
  D[9]  = 0.5f*(q1x*q2x - q1y*q2y);
  D[10] = 6.f*q2x*q2y;
  D[11] = 6.f*q2y*q2z;
  D[12] = 0.5f*(3.f*q2z*q2z - 1.f);
  D[13] = 6.f*q2x*q2z;
  D[14] = 1.5f*(q2x*q2x - q2y*q2y);
  D[15] = q0x*q2y + q2x*q0y;
  D[16] = q0y*q2z + q2y*q0z;
  D[17] = 0.5f*(q0z*q2z);
  D[18] = q0x*q2z + q2x*q0z;
  D[19] = 0.5f*(q0x*q2x - q0y*q2y);
  D[20] = 2.f*(q0x*q0y - q1x*q1y);
  D[21] = 2.f*(q0y*q0z - q1y*q1z);
  D[22] = 0.5f*(q0z*q0z - q1z*q1z);
  D[23] = 2.f*(q0x*q0z - q1x*q1z);
  D[24] = 0.5f*((q0x*q0x - q1x*q1x) - (q0y*q0y - q1y*q1y));
}

// ---------------------------------------------------------------- K0: split latents into bf16 hi/lo
__global__ void k0_latpack(const float* __restrict__ lat,
                           ushort_t* __restrict__ lath, ushort_t* __restrict__ latl) {
  int idx = blockIdx.x*256 + threadIdx.x;
  if (idx >= E_TOT*128) return;
  float x = lat[idx];
  ushort_t h = f2bf(x);
  float hf = __uint_as_float(((uint_t)h) << 16);
  lath[idx] = h;
  latl[idx] = f2bf(x - hf);
}

// ------------------------------------- K_pack: W_tp -> permuted MFMA-fragment bf16 hi/lo
// Job list: j<80: w0 col o=j (ilen 112); 80..103: w1r o (48); 104..127: w1i o (48);
// 128..135: w2r o (16); 136..143: w2i o (16). Tiles: 720 of 16(i)x16... M=16 i per tile.
// Layout (ushort units): frag(nt,kc,s)[lane][8] at ((nt*8 + kc*2 + s)*512 + lane*8)
__global__ void k_pack(const float* __restrict__ Wtp, ushort_t* __restrict__ Wp) {
  const int nt = blockIdx.x;
  const int t = threadIdx.x;
  const int kc = t >> 6, lane = t & 63;
  const int m = lane & 15, kg = lane >> 4;
  int j, mt;
  if (nt < 560)      { j = nt/7; mt = nt - j*7; }
  else if (nt < 704) { int r = nt-560; int p = r/3; j = 80+p; mt = r - p*3; }
  else               { j = 128 + (nt-704); mt = 0; }
  const int i = mt*16 + m;
  int c; float sc;
  if (j < 80)       { c = i*80 + j;               sc = SC0; }
  else if (j < 104) { c = 8960  + i*24 + (j-80);  sc = SC1; }
  else if (j < 128) { c = 10112 + i*24 + (j-104); sc = SC1; }
  else if (j < 136) { c = 11264 + i*8  + (j-128); sc = SC2; }
  else              { c = 11392 + i*8  + (j-136); sc = SC2; }
  ushort_t hi[8], lo[8];
#pragma unroll
  for (int jj = 0; jj < 8; ++jj) {
    int l = kc*32 + kg*8 + jj;
    float w = Wtp[(size_t)l*NCOL + c] * sc;
    ushort_t h = f2bf(w);
    float hf = __uint_as_float(((uint_t)h) << 16);
    hi[jj] = h;
    lo[jj] = f2bf(w - hf);
  }
  size_t base = ((size_t)nt*8 + kc*2)*512 + (size_t)lane*8;
#pragma unroll
  for (int jj = 0; jj < 8; ++jj) {
    Wp[base + jj]       = hi[jj];
    Wp[base + 512 + jj] = lo[jj];
  }
}

// ---------------------------------------------------------------- K1: _sln
__global__ void k1_sln(const float* __restrict__ x_all,
                       const float* __restrict__ w0, const float* __restrict__ b0,
                       const float* __restrict__ w1, const float* __restrict__ w2,
                       float* __restrict__ nf) {
  const int n = blockIdx.x;
  const int t = threadIdx.x;
  const float* x = x_all + n*120;
  float xs = (t < 32) ? x[t] : 0.f;
  float ssum = wsum(xs);
  float ssq  = wsum(xs*xs);
  float mu   = ssum * (1.f/32.f);
  float var  = ssq * (1.f/32.f) - mu*mu;
  float istd = rsqrtf(var + EPSF);
  float q1 = (t < 48) ? x[32+t] : 0.f;
  float v1s = wsum(q1*q1);
  float q2 = (t < 40) ? x[80+t] : 0.f;
  float v2s = wsum(q2*q2);
  float inv = rsqrtf(0.5f*(v1s*(1.f/48.f) + v2s*(1.f/40.f)) + EPSF);
  for (int j = t; j < 120; j += 64) {
    float val = x[j], r;
    if (j < 32)      r = (val - mu)*istd*w0[j] + b0[j];
    else if (j < 80) r = val*inv*w1[(j-32)/3];
    else             r = val*inv*w2[(j-80)/5];
    nf[n*120 + j] = r;
  }
}

// ------------------------------------------------- K2: per-edge preprocessing
__global__ void k2_edge_prep(const float* __restrict__ hid,
                             const float* __restrict__ evec,
                             const int*   __restrict__ eidx,
                             const int*   __restrict__ act,
                             const float* __restrict__ nf,
                             float* __restrict__ invec,
                             float* __restrict__ Rm,
                             float* __restrict__ D2bm) {
  const int e = blockIdx.x*blockDim.x + threadIdx.x;
  if (e >= E_TOT) return;
  const int ae  = act[e];
  const int ctr = eidx[ae];
  float vx = evec[ae*3+0], vy = evec[ae*3+1], vz = evec[ae*3+2];
  float rn = rsqrtf(vx*vx + vy*vy + vz*vz);
  float nx = vx*rn, ny = vy*rn, nz = vz*rn;
  float e1x, e1y, e1z;
  if (fabsf(nz) < 0.99f) { e1x = -ny; e1y = nx;  e1z = 0.f; }
  else                   { e1x = 0.f; e1y = -nz; e1z = ny;  }
  float rl = rsqrtf(e1x*e1x + e1y*e1y + e1z*e1z);
  e1x *= rl; e1y *= rl; e1z *= rl;
  float e2x = ny*e1z - nz*e1y;
  float e2y = nz*e1x - nx*e1z;
  float e2z = nx*e1y - ny*e1x;
  float R[9] = {e1x,e1y,e1z, e2x,e2y,e2z, nx,ny,nz};
#pragma unroll
  for (int j = 0; j < 9; ++j) Rm[e*9 + j] = R[j];
  float Df[25];
  wigner5(R, Df);
  float Rt[9] = {R[0],R[3],R[6], R[1],R[4],R[7], R[2],R[5],R[8]};
  float Db[25];
  wigner5(Rt, Db);
#pragma unroll
  for (int j = 0; j < 25; ++j) D2bm[e*25 + j] = Db[j];
  const float* xa = nf  + (size_t)ctr*120;
  const float* xb = hid + (size_t)e*120;
  float* iv = invec + (size_t)e*240;
  // layout: in0 @0 (112) | inn1 @112 (48) | inp1 @160 (48) | inn2 @208 (16) | inp2 @224 (16)
#pragma unroll
  for (int j = 0; j < 32; ++j) { iv[j] = xa[j]; iv[32+j] = xb[j]; }
#pragma unroll
  for (int u = 0; u < 32; ++u) {
    const float* src = (u < 16) ? (xa + 32 + 3*u) : (xb + 32 + 3*(u-16));
    float px = src[0], py = src[1], pz = src[2];
    float rx = R[0]*px + R[1]*py + R[2]*pz;
    float ry = R[3]*px + R[4]*py + R[5]*pz;
    float rz = R[6]*px + R[7]*py + R[8]*pz;
    iv[64+u]  = ry;
    iv[112+u] = rx;
    iv[160+u] = rz;
  }
#pragma unroll
  for (int u = 0; u < 16; ++u) {
    const float* src = (u < 8) ? (xa + 80 + 5*u) : (xb + 80 + 5*(u-8));
    float p0 = src[0], p1 = src[1], p2 = src[2], p3 = src[3], p4 = src[4];
    float d[5];
#pragma unroll
    for (int i = 0; i < 5; ++i)
      d[i] = Df[i*5+0]*p0 + Df[i*5+1]*p1 + Df[i*5+2]*p2 + Df[i*5+3]*p3 + Df[i*5+4]*p4;
    iv[96+u]  = d[2];
    iv[144+u] = d[1];
    iv[192+u] = d[3];
    iv[208+u] = d[0];
    iv[224+u] = d[4];
  }
}

// ------------------------------------------------- K2w: wenv = latents[ae] @ W_env / sqrt(128)
__global__ void k2_wenv(const float* __restrict__ lat, const float* __restrict__ Wenv,
                        const int* __restrict__ act, float* __restrict__ wenvo) {
  const int e = blockIdx.x*4 + (threadIdx.x >> 6);
  const int o = threadIdx.x & 63;
  if (o >= 56) return;
  const int ae = act[e];
  const float* lrow = lat + (size_t)ae*128;
  float s = 0.f;
  for (int l = 0; l < 128; ++l) s += lrow[l]*Wenv[l*56 + o];
  wenvo[(size_t)e*56 + o] = s * INV_SQRT128;
}

// --------------------------- K3: MFMA GEMM (split-bf16) fused with so2 contraction
// Block: 256 thr (4 waves), 32 edges; blockIdx.y = job half. Each wave: 90 tiles.
__global__ __launch_bounds__(256, 3)
void k3_gemm(const ushort_t* __restrict__ Wp,
             const ushort_t* __restrict__ lath,
             const ushort_t* __restrict__ latl,
             const float*  __restrict__ invg,
             float* __restrict__ oa_g) {
  __shared__ float in_lds[32*244];   // stride 244 to break bank conflicts
  const int t = threadIdx.x;
  const int eb = blockIdx.x;
  for (int i = t; i < 32*240; i += 256) {
    int e = i/240, r = i - e*240;
    in_lds[e*244 + r] = invg[(size_t)(eb*32 + e)*240 + r];
  }
  const int wave = t >> 6, lane = t & 63;
  const int le = lane & 15, g = lane >> 4;
  bf16x8 Bh[4][2], Bl[4][2];
  {
    const int e0 = eb*32 + le;
    const int ko = g*8;
#pragma unroll
    for (int kc = 0; kc < 4; ++kc) {
#pragma unroll
      for (int n = 0; n < 2; ++n) {
        size_t off = (size_t)(e0 + 16*n)*128 + kc*32 + ko;
        Bh[kc][n] = *(const bf16x8*)(lath + off);
        Bl[kc][n] = *(const bf16x8*)(latl + off);
      }
    }
  }
  __syncthreads();
  int nt = (blockIdx.y*4 + wave)*90;
  const int ntEnd = nt + 90;
  const int i0b = g*4;
  while (nt < ntEnd) {
    int j, jb, T;
    if (nt < 560)      { j = nt/7;  jb = j*7;  T = 7; }
    else if (nt < 704) { int r = nt - 560; int p = r/3; j = 80 + p; jb = 560 + p*3; T = 3; }
    else               { j = 128 + (nt - 704); jb = nt; T = 1; }
    int mt = nt - jb;
    int cnt = T - mt; { int rem = ntEnd - nt; if (cnt > rem) cnt = rem; }
    int ibA, ibB = 0, slotA, slotB = 0, two;
    float sA = 1.f;
    if (j < 80)       { two = 0; ibA = 0;   slotA = j; }
    else if (j < 104) { two = 1; int o = j-80;  ibA = 160; slotA = 80+o;            ibB = 112; slotB = 104+o; }
    else if (j < 128) { two = 1; int o = j-104; ibA = 112; slotA = 80+o; sA = -1.f; ibB = 160; slotB = 104+o; }
    else if (j < 136) { two = 1; int o = j-128; ibA = 224; slotA = 128+o;           ibB = 208; slotB = 136+o; }
    else              { two = 1; int o = j-136; ibA = 208; slotA = 128+o; sA = -1.f; ibB = 224; slotB = 136+o; }
    float aA0=0.f, aA1=0.f, aB0=0.f, aB1=0.f;
    for (int s = 0; s < cnt; ++s, ++nt, ++mt) {
      const bf16x8* ap = (const bf16x8*)Wp + (size_t)nt*512 + lane;
      f32x4 d0 = {0.f,0.f,0.f,0.f}, d1 = {0.f,0.f,0.f,0.f};
#pragma unroll
      for (int kc = 0; kc < 4; ++kc) {
        bf16x8 Ah = ap[(kc*2+0)*64];
        bf16x8 Al = ap[(kc*2+1)*64];
        d0 = __builtin_amdgcn_mfma_f32_16x16x32_bf16(Ah, Bh[kc][0], d0, 0, 0, 0);
        d1 = __builtin_amdgcn_mfma_f32_16x16x32_bf16(Ah, Bh[kc][1], d1, 0, 0, 0);
        d0 = __builtin_amdgcn_mfma_f32_16x16x32_bf16(Ah, Bl[kc][0], d0, 0, 0, 0);
        d1 = __builtin_amdgcn_mfma_f32_16x16x32_bf16(Ah, Bl[kc][1], d1, 0, 0, 0);
        d0 = __builtin_amdgcn_mfma_f32_16x16x32_bf16(Al, Bh[kc][0], d0, 0, 0, 0);
        d1 = __builtin_amdgcn_mfma_f32_16x16x32_bf16(Al, Bh[kc][1], d1, 0, 0, 0);
      }
      const int i0 = mt*16 + i0b;
      f32x4 iA0 = *(const f32x4*)&in_lds[le*244 + ibA + i0];
      f32x4 iA1 = *(const f32x4*)&in_lds[(le+16)*244 + ibA + i0];
      aA0 += d0[0]*iA0[0] + d0[1]*iA0[1] + d0[2]*iA0[2] + d0[3]*iA0[3];
      aA1 += d1[0]*iA1[0] + d1[1]*iA1[1] + d1[2]*iA1[2] + d1[3]*iA1[3];
      if (two) {
        f32x4 iB0 = *(const f32x4*)&in_lds[le*244 + ibB + i0];
        f32x4 iB1 = *(const f32x4*)&in_lds[(le+16)*244 + ibB + i0];
        aB0 += d0[0]*iB0[0] + d0[1]*iB0[1] + d0[2]*iB0[2] + d0[3]*iB0[3];
        aB1 += d1[0]*iB1[0] + d1[1]*iB1[1] + d1[2]*iB1[2] + d1[3]*iB1[3];
      }
    }
    aA0 += __shfl_xor(aA0, 16, 64); aA0 += __shfl_xor(aA0, 32, 64);
    aA1 += __shfl_xor(aA1, 16, 64); aA1 += __shfl_xor(aA1, 32, 64);
    if (two) {
      aB0 += __shfl_xor(aB0, 16, 64); aB0 += __shfl_xor(aB0, 32, 64);
      aB1 += __shfl_xor(aB1, 16, 64); aB1 += __shfl_xor(aB1, 32, 64);
    }
    if (lane < 16)      atomicAdd(&oa_g[(size_t)(eb*32 + le)*144 + slotA], sA*aA0);
    else if (lane < 32) atomicAdd(&oa_g[(size_t)(eb*32 + 16 + le)*144 + slotA], sA*aA1);
    else if (lane < 48) { if (two) atomicAdd(&oa_g[(size_t)(eb*32 + le)*144 + slotB], aB0); }
    else                { if (two) atomicAdd(&oa_g[(size_t)(eb*32 + 16 + le)*144 + slotB], aB1); }
  }
}

// -------------------------------------------- K4: per-edge epilogue (wave per edge)
__global__ __launch_bounds__(256)
void k4_epi(const float* __restrict__ oa_g, const float* __restrict__ Rm,
            const float* __restrict__ D2bm, const float* __restrict__ wenvg,
            const int* __restrict__ eidx, const int* __restrict__ act,
            const float* __restrict__ Wp0, const float* __restrict__ bp0,
            const float* __restrict__ Wp1, const float* __restrict__ Wp2,
            float* __restrict__ accg) {
  __shared__ float sc[4][160];    // gates 0..55 | y1g 56..103 | y2g 104..143
  const int wave = threadIdx.x >> 6, lane = threadIdx.x & 63;
  const int eg = blockIdx.x*4 + wave;
  const float* o_ = oa_g + (size_t)eg*144;
  if (lane < 56) {
    float v = o_[lane];
    sc[wave][lane] = (lane < 32) ? v/(1.f + expf(-v)) : 1.f/(1.f + expf(-v));
  }
  __syncthreads();
  const float* Rr = Rm + (size_t)eg*9;
  const float* Db = D2bm + (size_t)eg*25;
  if (lane < 48) {
    int u = lane/3, cc = lane - u*3;
    float yx = o_[104+u], yy = o_[56+u], yz = o_[80+u];
    float p = Rr[cc]*yx + Rr[3+cc]*yy + Rr[6+cc]*yz;     // R^T back-rotation
    sc[wave][56+lane] = p * sc[wave][32+u];
  }
  if (lane >= 48 && lane < 56) {  // help start y2g early: u = lane-48 in 0..7, comp 0
    // (no-op; y2g handled below for all 40 by lanes 0..39 after sync)
  }
  __syncthreads();
  if (lane < 40) {
    int u = lane/5, ii = lane - u*5;
    float y0 = o_[136+u], y1v = o_[120+u], y2v = o_[72+u], y3 = o_[96+u], y4 = o_[128+u];
    float p = Db[ii*5+0]*y0 + Db[ii*5+1]*y1v + Db[ii*5+2]*y2v + Db[ii*5+3]*y3 + Db[ii*5+4]*y4;
    sc[wave][104+lane] = p * sc[wave][48+u];
  }
  __syncthreads();
  const float* we = wenvg + (size_t)eg*56;
  const int ctr = eidx[act[eg]];
  float* dst = accg + (size_t)ctr*120;
#pragma unroll
  for (int rnd = 0; rnd < 2; ++rnd) {
    int jo = rnd*64 + lane;
    if (jo < 120) {
      float val;
      if (jo < 32) {
        float s = 0.f;
#pragma unroll
        for (int i2 = 0; i2 < 32; ++i2) s += sc[wave][i2]*Wp0[i2*32 + jo];
        val = (s*INV_SQRT32 + bp0[jo]) * we[jo];
      } else if (jo < 80) {
        int jj = jo-32, v = jj/3, cc = jj - v*3;
        float s = 0.f;
#pragma unroll
        for (int u = 0; u < 16; ++u) s += sc[wave][56 + u*3 + cc]*Wp1[u*16 + v];
        val = s*INV_SQRT16*we[32+v];
      } else {
        int jj = jo-80, v = jj/5, ii = jj - v*5;
        float s = 0.f;
#pragma unroll
        for (int u = 0; u < 8; ++u) s += sc[wave][104 + u*5 + ii]*Wp2[u*8 + v];
        val = s*INV_SQRT8*we[48+v];
      }
      atomicAdd(&dst[jo], val);
    }
  }
}

// -------------------------------------------- K5: residual path + combine
__global__ void k5_final(const float* __restrict__ x_all,
                         const float* __restrict__ Wr0, const float* __restrict__ br0,
                         const float* __restrict__ Wr1, const float* __restrict__ Wr2,
                         const float* __restrict__ accg,
                         float* __restrict__ out) {
  const int n = blockIdx.x;
  const int t = threadIdx.x;
  if (t >= 120) return;
  const float* x = x_all + n*120;
  float r;
  if (t < 32) {
    float s = 0.f;
#pragma unroll
    for (int i = 0; i < 32; ++i) s += x[i]*Wr0[i*32 + t];
    r = s*INV_SQRT32 + br0[t];
  } else if (t < 80) {
    int j = t - 32, v = j/3, cp = j - 3*v;
    float s = 0.f;
#pragma unroll
    for (int u = 0; u < 16; ++u) s += x[32 + u*3 + cp]*Wr1[u*16 + v];
    r = s*INV_SQRT16;
  } else {
    int j = t - 80, v = j/5, cp = j - 5*v;
    float s = 0.f;
#pragma unroll
    for (int u = 0; u < 8; ++u) s += x[80 + u*5 + cp]*Wr2[u*8 + v];
    r = s*INV_SQRT8;
  }
  out[n*120 + t] = C_NEW_*(NORMC*accg[n*120 + t]) + C_OLD_*r;
}

// ---------------------------------------------------------------- launcher
extern "C" void kernel_launch(void* const* d_in, const int* in_sizes, int n_in,
                              void* d_out, int out_size, void* d_ws, size_t ws_size,
                              hipStream_t stream) {
  const float* lat  = (const float*)d_in[0];
  const float* ndf  = (const float*)d_in[1];
  const float* hid  = (const float*)d_in[2];
  const float* evec = (const float*)d_in[4];
  const float* Wtp  = (const float*)d_in[5];
  const float* Wenv = (const float*)d_in[6];
  const float* w0   = (const float*)d_in[7];
  const float* b0   = (const float*)d_in[8];
  const float* w1   = (const float*)d_in[9];
  const float* w2   = (const float*)d_in[10];
  const float* Wp0  = (const float*)d_in[11];
  const float* bp0  = (const float*)d_in[12];
  const float* Wp1  = (const float*)d_in[13];
  const float* Wp2  = (const float*)d_in[14];
  const float* Wr0  = (const float*)d_in[15];
  const float* br0  = (const float*)d_in[16];
  const float* Wr1  = (const float*)d_in[17];
  const float* Wr2  = (const float*)d_in[18];
  const int*   eidx = (const int*)d_in[20];
  const int*   act  = (const int*)d_in[21];
  float* out = (float*)d_out;

  char* p = (char*)d_ws;
  float*    nf    = (float*)(p);                       // 512*120*4      = 245760
  float*    invec = (float*)(p + 245760);              // 10240*240*4    = 9830400
  float*    Rm    = (float*)(p + 10076160);            // 10240*9*4      = 368640
  float*    D2bm  = (float*)(p + 10444800);            // 10240*25*4     = 1024000
  float*    wenv  = (float*)(p + 11468800);            // 10240*56*4     = 2293760
  float*    accg  = (float*)(p + 13762560);            // 512*120*4      = 245760
  float*    oa_g  = (float*)(p + 14008320);            // 10240*144*4    = 5898240
  ushort_t* lath  = (ushort_t*)(p + 19906560);         // 10240*128*2    = 2621440
  ushort_t* latl  = (ushort_t*)(p + 22528000);         // 2621440
  ushort_t* Wpack = (ushort_t*)(p + 25149440);         // 720*8*512*2    = 5898240  (end 31047680)

  hipMemsetAsync(accg, 0, 245760, stream);
  hipMemsetAsync(oa_g, 0, 5898240, stream);
  k0_latpack<<<(E_TOT*128 + 255)/256, 256, 0, stream>>>(lat, lath, latl);
  k_pack<<<720, 256, 0, stream>>>(Wtp, Wpack);
  k1_sln<<<N_NODES, 64, 0, stream>>>(ndf, w0, b0, w1, w2, nf);
  k2_edge_prep<<<E_TOT/256, 256, 0, stream>>>(hid, evec, eidx, act, nf, invec, Rm, D2bm);
  k2_wenv<<<E_TOT/4, 256, 0, stream>>>(lat, Wenv, act, wenv);
  k3_gemm<<<dim3(E_TOT/32, 2), 256, 0, stream>>>(Wpack, lath, latl, invec, oa_g);
  k4_epi<<<E_TOT/4, 256, 0, stream>>>(oa_g, Rm, D2bm, wenv, eidx, act, Wp0, bp0, Wp1, Wp2, accg);
  k5_final<<<N_NODES, 128, 0, stream>>>(ndf, Wr0, br0, Wr1, Wr2, accg, out);
}